// Round 18
// baseline (513.481 us; speedup 1.0000x reference)
//
#include <hip/hip_runtime.h>

typedef _Float16 h2v __attribute__((ext_vector_type(2)));
typedef _Float16 h4v __attribute__((ext_vector_type(4)));
typedef _Float16 h8v __attribute__((ext_vector_type(8)));
typedef float    f4v __attribute__((ext_vector_type(4)));
typedef unsigned int u32;
typedef unsigned long long u64;

#define WUP_STRIDE 264        // wup padded row (halves)

// LDS layout (bytes) for fused_k (1024 threads)
// GEMM phase: WT quad (4x16640) + TT single (18432, wave-local) + WWS quad
// (4x16384) = 150528 B. GC (full G, 135168) + VS overlay it after the GEMMs.
#define WT_FRAG_STRIDE 1040   // 64 lanes*16B + 16B pad (bank spread)
#define WT_SLOT(s) ((s) * 16640)          // 4 slots: [0, 66560)
#define TT_OFF    66560       // single buffer, wave-local rows
#define TT_STRIDE 36
#define WWS_OFF   84992       // 4 slots x 16384: [84992, 150528)
#define GC_OFF    0           // full G 256 x 264 halves = 135168 B (after GEMM)
#define GC_STRIDE 264
#define VS_OFF    135168      // 2 x 2048 B ([h*2^-7 ; -c*2^-7])
#define LDS_FUSED 150528

__device__ inline f4v mfma16(h8v a, h8v b, f4v c) {
  return __builtin_amdgcn_mfma_f32_16x16x32_f16(a, b, c, 0, 0, 0);
}

__device__ inline u64 cvt4(f4v v) {
  h4v d; d[0] = (_Float16)v[0]; d[1] = (_Float16)v[1];
  d[2] = (_Float16)v[2]; d[3] = (_Float16)v[3];
  return __builtin_bit_cast(u64, d);
}

// raw barrier: LDS-visibility only, never drains vmcnt
#define BAR() { asm volatile("s_waitcnt lgkmcnt(0)" ::: "memory"); \
                __builtin_amdgcn_s_barrier(); \
                asm volatile("" ::: "memory"); }

// fragment loader: ROW-BASE pointer; kk/g offsets applied exactly once
#define LDH(basep, kk, dst) { \
    h4v lo_ = *(const h4v*)((basep) + (kk)*32 + 4*g); \
    h4v hi_ = *(const h4v*)((basep) + (kk)*32 + 16 + 4*g); \
    dst = __builtin_shufflevector(lo_, hi_, 0, 1, 2, 3, 4, 5, 6, 7); }

// ---- prep: Wu padded row-major (A-frag source for the recurrence) ----
__global__ void prep_k(const float* __restrict__ Wu, _Float16* __restrict__ wup)
{
  int j = blockIdx.x, k = threadIdx.x;
  wup[j * WUP_STRIDE + k] = (_Float16)Wu[j * 256 + k];
  if (k < 8) wup[j * WUP_STRIDE + 256 + k] = (_Float16)0.f;
}

// ---- prep2: pack Wv (wvp) and Ww (wwp2, t-sliced) into MFMA B-frag order ----
// koff(g,h) = h<4 ? 4g+h : 16+4g+(h-4)
// wvp [(nt*8+kk)*64+lane]*8+h  = Wv[kk*32+koff][nt*16+l15]
// wwp2[(tau*16+it)*64+lane]*8+h = Ww[it*16+l15][tau*32+koff]
__global__ void prep2_k(const float* __restrict__ Wv, const float* __restrict__ Ww,
                        _Float16* __restrict__ wvp, _Float16* __restrict__ wwp2)
{
  int b = blockIdx.x;
  int tid = threadIdx.x;
  int lane = tid & 63, q = tid >> 6;
  int g2 = (lane >> 4) & 3, l15 = lane & 15;
  if (b < 128) {
    int nt = b >> 3, kk = b & 7;
    int j = nt * 16 + l15;
    _Float16* dst = wvp + ((size_t)(b * 64 + lane)) * 8;
#pragma unroll
    for (int e = 0; e < 2; ++e) {
      int h = 2 * q + e;
      int k = kk * 32 + (h < 4 ? 4 * g2 + h : 16 + 4 * g2 + (h - 4));
      dst[h] = (_Float16)Wv[(size_t)k * 256 + j];
    }
  } else {
    int s = b - 128;                 // tau*16 + it
    int it = s & 15;
    int tau = s >> 4;
    int i = it * 16 + l15;
    _Float16* dst = wwp2 + ((size_t)(s * 64 + lane)) * 8;
#pragma unroll
    for (int e = 0; e < 2; ++e) {
      int h = 2 * q + e;
      int t = tau * 32 + (h < 4 ? 4 * g2 + h : 16 + 4 * g2 + (h - 4));
      dst[h] = (_Float16)Ww[(size_t)i * 256 + t];
    }
  }
}

// out[b,i] = sum_j M[i,j] * V[b,j] for 8 batches per block.
__global__ void matvec8_k(const float* __restrict__ M, const float* __restrict__ V,
                          float* __restrict__ out)
{
  __shared__ float vb[8][256];
  const int i = threadIdx.x;
  const int b0 = blockIdx.x * 8;
#pragma unroll
  for (int r = 0; r < 8; ++r)
    vb[r][i] = V[(size_t)(b0 + r) * 256 + i];
  __syncthreads();
  float acc[8];
#pragma unroll
  for (int r = 0; r < 8; ++r) acc[r] = 0.f;
#pragma unroll 4
  for (int j = 0; j < 256; j += 4) {
    f4v m = *(const f4v*)(M + (size_t)i * 256 + j);
#pragma unroll
    for (int r = 0; r < 8; ++r) {
      f4v v = *(const f4v*)(&vb[r][j]);
      acc[r] += m[0] * v[0] + m[1] * v[1] + m[2] * v[2] + m[3] * v[3];
    }
  }
#pragma unroll
  for (int r = 0; r < 8; ++r)
    out[(size_t)(b0 + r) * 256 + i] = acc[r];
}

// ================= fused (1024 thr, 16 waves, 1 batch/block) ================
// vs round 17: 2-tau phases (4 barriers in GEMM loop, was 8). TT is wave-local
// (each wave writes/reads only its own j-rows) -> single buffer, no barrier;
// E(tau) runs same-phase after D(tau); E(2p) interleaves with C(2p+1) for ILP.
// WT/WWS quad-buffered: phase p reads slots {2p,2p+1}, writes {2p+2,2p+3} --
// all residues distinct, one end-of-phase barrier covers everything.
// Recurrence: round-15-proven form (no loop-carried MFMA accumulators).
__global__ __launch_bounds__(1024, 1) void fused_k(
    const float* __restrict__ w, const _Float16* __restrict__ wvp,
    const _Float16* __restrict__ wwp2, const _Float16* __restrict__ wup,
    const float* __restrict__ beta, float* __restrict__ cout)
{
  extern __shared__ char smem[];
  _Float16* const TT = (_Float16*)(smem + TT_OFF);

  const int tid = threadIdx.x;
  const int wv = tid >> 6, lane = tid & 63;
  const int g = (lane >> 4) & 3, l15 = lane & 15;
  const int st_t = tid >> 5;            // staging row 0..31
  const int st_c = (tid & 31) * 8;      // staging col base (floats)
  const int B   = blockIdx.x;
  const float* wb = w + (size_t)B * 65536;

  // frag-order staging decomposition (round-15-verified mapping)
  const int c_   = tid & 31;
  const int wt_woff = ((c_ >> 2) * 2 + (st_t >> 4)) * WT_FRAG_STRIDE
                    + ((c_ & 1) * 32 + (st_t & 15)) * 16 + ((c_ >> 1) & 1) * 8;
#define WT_WRITE(off) { char* fb_ = smem + (off) + wt_woff; \
    *(u64*)fb_ = cvt4(sw[0]); *(u64*)(fb_ + 256) = cvt4(sw[1]); }

  f4v sw[2];                            // staged w tile (one set in flight)
  uint4 sws;                            // staged wwp2 slice

  // ---- GEMM1 B-frags: fixed per wave, loaded once, reused all taus ----
  h8v bfv[8];
#pragma unroll
  for (int kk = 0; kk < 8; ++kk)
    bfv[kk] = *(const h8v*)(wvp + ((size_t)((wv * 8 + kk) * 64 + lane)) * 8);

  // prologue: tiles/slices 0,1 -> slots 0,1; reg-stage tile/slice 2
  {
    const float* src0 = wb + (size_t)st_t * 256 + st_c;
    sw[0] = *(const f4v*)(src0);
    sw[1] = *(const f4v*)(src0 + 4);
    WT_WRITE(WT_SLOT(0));
    *(uint4*)(smem + WWS_OFF + tid * 16) =
        *(const uint4*)((const char*)wwp2 + tid * 16);
    const float* src1 = wb + (size_t)(32 + st_t) * 256 + st_c;
    sw[0] = *(const f4v*)(src1);
    sw[1] = *(const f4v*)(src1 + 4);
    WT_WRITE(WT_SLOT(1));
    *(uint4*)(smem + WWS_OFF + 16384 + tid * 16) =
        *(const uint4*)((const char*)wwp2 + 16384 + tid * 16);
    const float* src2 = wb + (size_t)(64 + st_t) * 256 + st_c;
    sw[0] = *(const f4v*)(src2);
    sw[1] = *(const f4v*)(src2 + 4);
    sws = *(const uint4*)((const char*)wwp2 + 2 * 16384 + tid * 16);
    BAR();
  }

  f4v acc2[16];
#pragma unroll
  for (int it = 0; it < 16; ++it) acc2[it] = f4v{0.f, 0.f, 0.f, 0.f};

#pragma unroll
  for (int p = 0; p < 4; ++p) {
    const int tA = 2 * p, tB = 2 * p + 1;
    // S1: stage-write tile/slice (tA+2) from regs loaded last phase
    if (p < 3) {
      WT_WRITE(WT_SLOT((tA + 2) & 3));
      *(uint4*)(smem + WWS_OFF + ((tA + 2) & 3) * 16384 + tid * 16) = sws;
    }
    // S2: issue loads for tile/slice (tB+2)
    if (p < 3) {
      const float* src = wb + (size_t)((tB + 2) * 32 + st_t) * 256 + st_c;
      sw[0] = *(const f4v*)(src);
      sw[1] = *(const f4v*)(src + 4);
      sws = *(const uint4*)((const char*)wwp2 + (size_t)(tB + 2) * 16384 + tid * 16);
    }
    // C(tA): GEMM1 -- contiguous b128 A-frags from frag-order WT
    f4v acc1[2];
    acc1[0] = f4v{0.f, 0.f, 0.f, 0.f};
    acc1[1] = f4v{0.f, 0.f, 0.f, 0.f};
    {
      const char* wtc = smem + WT_SLOT(tA & 3);
#pragma unroll
      for (int kk = 0; kk < 8; ++kk) {
        h8v a0 = *(const h8v*)(wtc + (kk * 2) * WT_FRAG_STRIDE + lane * 16);
        h8v a1 = *(const h8v*)(wtc + (kk * 2 + 1) * WT_FRAG_STRIDE + lane * 16);
        acc1[0] = mfma16(a0, bfv[kk], acc1[0]);
        acc1[1] = mfma16(a1, bfv[kk], acc1[1]);
      }
    }
    // D(tA): TT write (wave-local rows)
#pragma unroll
    for (int tm = 0; tm < 2; ++tm) {
      f4v a = acc1[tm];
      h4v t4; t4[0] = (_Float16)a[0]; t4[1] = (_Float16)a[1];
      t4[2] = (_Float16)a[2]; t4[3] = (_Float16)a[3];
      *(h4v*)(TT + (wv * 16 + l15) * TT_STRIDE + tm * 16 + g * 4) = t4;
    }
    // S3: stage-write tile/slice (tB+2) from regs loaded at S2
    if (p < 3) {
      WT_WRITE(WT_SLOT((tB + 2) & 3));
      *(uint4*)(smem + WWS_OFF + ((tB + 2) & 3) * 16384 + tid * 16) = sws;
    }
    // S4: issue loads for tile/slice (tA+4) (consumed next phase S1)
    if (p < 2) {
      const float* src = wb + (size_t)((tA + 4) * 32 + st_t) * 256 + st_c;
      sw[0] = *(const f4v*)(src);
      sw[1] = *(const f4v*)(src + 4);
      sws = *(const uint4*)((const char*)wwp2 + (size_t)(tA + 4) * 16384 + tid * 16);
    }
    __builtin_amdgcn_s_setprio(1);
    // E(tA): GEMM2 (wave-local TT read + WWS[tA&3]) -- independent of C(tB)
    {
      h8v a0p; LDH(TT + (wv * 16 + l15) * TT_STRIDE, 0, a0p);
      const char* wws = smem + WWS_OFF + (tA & 3) * 16384;
#pragma unroll
      for (int it = 0; it < 16; ++it) {
        h8v bf = *(const h8v*)(wws + (it * 64 + lane) * 16);
        acc2[it] = mfma16(a0p, bf, acc2[it]);
      }
    }
    // C(tB): GEMM1
    acc1[0] = f4v{0.f, 0.f, 0.f, 0.f};
    acc1[1] = f4v{0.f, 0.f, 0.f, 0.f};
    {
      const char* wtc = smem + WT_SLOT(tB & 3);
#pragma unroll
      for (int kk = 0; kk < 8; ++kk) {
        h8v a0 = *(const h8v*)(wtc + (kk * 2) * WT_FRAG_STRIDE + lane * 16);
        h8v a1 = *(const h8v*)(wtc + (kk * 2 + 1) * WT_FRAG_STRIDE + lane * 16);
        acc1[0] = mfma16(a0, bfv[kk], acc1[0]);
        acc1[1] = mfma16(a1, bfv[kk], acc1[1]);
      }
    }
    __builtin_amdgcn_s_setprio(0);
    // D(tB): TT write (in-wave WAR vs E(tA)'s reads -- DS ops in-order per wave)
#pragma unroll
    for (int tm = 0; tm < 2; ++tm) {
      f4v a = acc1[tm];
      h4v t4; t4[0] = (_Float16)a[0]; t4[1] = (_Float16)a[1];
      t4[2] = (_Float16)a[2]; t4[3] = (_Float16)a[3];
      *(h4v*)(TT + (wv * 16 + l15) * TT_STRIDE + tm * 16 + g * 4) = t4;
    }
    // E(tB): GEMM2
    {
      h8v a0p; LDH(TT + (wv * 16 + l15) * TT_STRIDE, 0, a0p);
      const char* wws = smem + WWS_OFF + (tB & 3) * 16384;
#pragma unroll
      for (int it = 0; it < 16; ++it) {
        h8v bf = *(const h8v*)(wws + (it * 64 + lane) * 16);
        acc2[it] = mfma16(a0p, bf, acc2[it]);
      }
    }
    // one barrier per PHASE (2 taus)
    BAR();
  } // phases

  // ---- write FULL G into LDS (overlays WT/TT/WWS; GEMM reads done) ----
  // lane holds acc2[it] = G[i = it*16 + l15][j = wv*16 + 4g + reg]
  {
    _Float16* const GC = (_Float16*)(smem + GC_OFF);
#pragma unroll
    for (int it = 0; it < 16; ++it) {
      const int i = it * 16 + l15;
      f4v a = acc2[it];
      h4v t4; t4[0] = (_Float16)a[0]; t4[1] = (_Float16)a[1];
      t4[2] = (_Float16)a[2]; t4[3] = (_Float16)a[3];
      *(h4v*)(GC + (size_t)i * GC_STRIDE + wv * 16 + g * 4) = t4;
    }
  }
  // zero VS buffer 0 (h=0, c=0)
  if (tid < 256) ((u64*)(smem + VS_OFF))[tid] = 0ull;
  BAR();   // G + VS0 visible

  // ---- load A-frags of [Wu | G] for this wave's 16-row i-tile ----
  h8v af[16];
  {
    const int arow = wv * 16 + l15;
    const _Float16* wurow = wup + (size_t)arow * WUP_STRIDE;
#pragma unroll
    for (int kk = 0; kk < 8; ++kk) { LDH(wurow, kk, af[kk]); }
    const _Float16* gcrow = (const _Float16*)(smem + GC_OFF) + (size_t)arow * GC_STRIDE;
#pragma unroll
    for (int kk = 0; kk < 8; ++kk) { LDH(gcrow, kk, af[8 + kk]); }
  }
  f4v beta4 = *(const f4v*)(beta + (size_t)B * 256 + wv * 16 + 4 * g);
  f4v cm4 = f4v{0.f, 0.f, 0.f, 0.f};

  // producer slot for this (wv,g): byte offset within VS h-part / c-part
  const int vslot = (wv >> 1) * 64 + g * 16 + (wv & 1) * 8;

  for (int t = 0; t < 20; ++t) {
    const char* vsr = smem + VS_OFF + (t & 1) * 2048;
    f4v c0 = f4v{0.f, 0.f, 0.f, 0.f}, c1 = f4v{0.f, 0.f, 0.f, 0.f};
    f4v c2 = f4v{0.f, 0.f, 0.f, 0.f}, c3 = f4v{0.f, 0.f, 0.f, 0.f};
    __builtin_amdgcn_s_setprio(1);
#pragma unroll
    for (int kk = 0; kk < 16; kk += 4) {
      h8v v0 = *(const h8v*)(vsr + kk * 64 + g * 16);
      h8v v1 = *(const h8v*)(vsr + (kk + 1) * 64 + g * 16);
      h8v v2 = *(const h8v*)(vsr + (kk + 2) * 64 + g * 16);
      h8v v3 = *(const h8v*)(vsr + (kk + 3) * 64 + g * 16);
      c0 = mfma16(af[kk], v0, c0);
      c1 = mfma16(af[kk + 1], v1, c1);
      c2 = mfma16(af[kk + 2], v2, c2);
      c3 = mfma16(af[kk + 3], v3, c3);
    }
    __builtin_amdgcn_s_setprio(0);
    f4v y4 = (c0 + c1) + (c2 + c3);   // every D-column equals y
#pragma unroll
    for (int r = 0; r < 4; ++r) {
      float y = beta4[r] + y4[r] * 128.f;
      float hv = fmaxf(y, 0.f);
      cm4[r] += hv;
      y4[r] = hv;                      // reuse as h storage
    }
    char* vsw = smem + VS_OFF + ((t + 1) & 1) * 2048;
    if (l15 == 0) {
      h4v hh, ch;
#pragma unroll
      for (int r = 0; r < 4; ++r) {
        hh[r] = (_Float16)(y4[r] * 0.0078125f);     //  h * 2^-7
        ch[r] = (_Float16)(-cm4[r] * 0.0078125f);   // -c * 2^-7
      }
      *(u64*)(vsw + vslot)       = __builtin_bit_cast(u64, hh);
      *(u64*)(vsw + 512 + vslot) = __builtin_bit_cast(u64, ch);
    }
    BAR();
  }
  if (l15 == 0)
    *(f4v*)(cout + (size_t)B * 256 + wv * 16 + 4 * g) = cm4;
}

extern "C" void kernel_launch(void* const* d_in, const int* in_sizes, int n_in,
                              void* d_out, int out_size, void* d_ws, size_t ws_size,
                              hipStream_t stream)
{
  const float* w  = (const float*)d_in[0];
  const float* b  = (const float*)d_in[1];
  const float* Ww = (const float*)d_in[2];
  const float* Wu = (const float*)d_in[3];
  const float* Wv = (const float*)d_in[4];

  char* ws = (char*)d_ws;
  float*    beta = (float*)(ws);
  float*    cbuf = (float*)(ws + (size_t)2 * 1024 * 1024);
  _Float16* wvp  = (_Float16*)(ws + (size_t)4 * 1024 * 1024);
  _Float16* wwp2 = (_Float16*)(ws + (size_t)4 * 1024 * 1024 + 131072);
  _Float16* wup  = (_Float16*)(ws + (size_t)4 * 1024 * 1024 + 262144);

  (void)in_sizes; (void)n_in; (void)out_size; (void)ws_size;

  hipFuncSetAttribute((const void*)fused_k,
                      hipFuncAttributeMaxDynamicSharedMemorySize, LDS_FUSED);

  prep_k<<<256, 256, 0, stream>>>(Wu, wup);
  prep2_k<<<256, 256, 0, stream>>>(Wv, Ww, wvp, wwp2);
  matvec8_k<<<256, 256, 0, stream>>>(Ww, b, beta);                  // beta = Ww @ b
  fused_k<<<2048, 1024, LDS_FUSED, stream>>>(w, wvp, wwp2, wup, beta, cbuf);
  matvec8_k<<<256, 256, 0, stream>>>(Wv, cbuf, (float*)d_out);      // x = Wv @ c
}

// Round 19
// 421.541 us; speedup vs baseline: 1.2181x; 1.2181x over previous
//
#include <hip/hip_runtime.h>

typedef _Float16 h2v __attribute__((ext_vector_type(2)));
typedef _Float16 h4v __attribute__((ext_vector_type(4)));
typedef _Float16 h8v __attribute__((ext_vector_type(8)));
typedef float    f4v __attribute__((ext_vector_type(4)));
typedef unsigned int u32;
typedef unsigned long long u64;

#define WUP_STRIDE 264        // wup padded row (halves)

// LDS layout (bytes) for fused_k (1024 threads)
// GEMM phase: WT(frag-order, dbuf) + TT(dbuf) + WWS(tribuf) = 119296 B,
// all inside the GC region (135168 B) which is written after the GEMMs.
// NOTE (r18 lesson): merging two taus per phase (quad-buffered WT/WWS, one
// barrier per 2 taus) widens the worst-phase live set past the 128-reg/16-wave
// unified budget -> per-phase scratch spills (+500 MB WRITE, 410->508 us).
// This 1-tau pipeline is just under the register edge. Do not widen it.
#define WT_FRAG_STRIDE 1040   // 64 lanes*16B + 16B pad (bank spread)
#define WT0_OFF   0
#define WT1_OFF   16640
#define TT0_OFF   33280       // 256 rows * 36 halves * 2 = 18432
#define TT1_OFF   51712
#define TT_STRIDE 36
#define WWS0_OFF  70144       // 3 slices x 16384 -> end 119296
#define GC_OFF    0           // full G 256 x 264 halves = 135168 B
#define GC_STRIDE 264
#define VS_OFF    135168      // 2 x 2048 B ([h*2^-7 ; -c*2^-7])
#define LDS_FUSED 139264

__device__ inline f4v mfma16(h8v a, h8v b, f4v c) {
  return __builtin_amdgcn_mfma_f32_16x16x32_f16(a, b, c, 0, 0, 0);
}

__device__ inline u64 cvt4(f4v v) {
  h4v d; d[0] = (_Float16)v[0]; d[1] = (_Float16)v[1];
  d[2] = (_Float16)v[2]; d[3] = (_Float16)v[3];
  return __builtin_bit_cast(u64, d);
}

// raw barrier: LDS-visibility only, never drains vmcnt
#define BAR() { asm volatile("s_waitcnt lgkmcnt(0)" ::: "memory"); \
                __builtin_amdgcn_s_barrier(); \
                asm volatile("" ::: "memory"); }

// fragment loader: ROW-BASE pointer; kk/g offsets applied exactly once
#define LDH(basep, kk, dst) { \
    h4v lo_ = *(const h4v*)((basep) + (kk)*32 + 4*g); \
    h4v hi_ = *(const h4v*)((basep) + (kk)*32 + 16 + 4*g); \
    dst = __builtin_shufflevector(lo_, hi_, 0, 1, 2, 3, 4, 5, 6, 7); }

// ---- prep: Wu padded row-major (A-frag source for the recurrence) ----
__global__ void prep_k(const float* __restrict__ Wu, _Float16* __restrict__ wup)
{
  int j = blockIdx.x, k = threadIdx.x;
  wup[j * WUP_STRIDE + k] = (_Float16)Wu[j * 256 + k];
  if (k < 8) wup[j * WUP_STRIDE + 256 + k] = (_Float16)0.f;
}

// ---- prep2: pack Wv (wvp) and Ww (wwp2, t-sliced) into MFMA B-frag order ----
// koff(g,h) = h<4 ? 4g+h : 16+4g+(h-4)
// wvp [(nt*8+kk)*64+lane]*8+h  = Wv[kk*32+koff][nt*16+l15]
// wwp2[(tau*16+it)*64+lane]*8+h = Ww[it*16+l15][tau*32+koff]
__global__ void prep2_k(const float* __restrict__ Wv, const float* __restrict__ Ww,
                        _Float16* __restrict__ wvp, _Float16* __restrict__ wwp2)
{
  int b = blockIdx.x;
  int tid = threadIdx.x;
  int lane = tid & 63, q = tid >> 6;
  int g2 = (lane >> 4) & 3, l15 = lane & 15;
  if (b < 128) {
    int nt = b >> 3, kk = b & 7;
    int j = nt * 16 + l15;
    _Float16* dst = wvp + ((size_t)(b * 64 + lane)) * 8;
#pragma unroll
    for (int e = 0; e < 2; ++e) {
      int h = 2 * q + e;
      int k = kk * 32 + (h < 4 ? 4 * g2 + h : 16 + 4 * g2 + (h - 4));
      dst[h] = (_Float16)Wv[(size_t)k * 256 + j];
    }
  } else {
    int s = b - 128;                 // tau*16 + it
    int it = s & 15;
    int tau = s >> 4;
    int i = it * 16 + l15;
    _Float16* dst = wwp2 + ((size_t)(s * 64 + lane)) * 8;
#pragma unroll
    for (int e = 0; e < 2; ++e) {
      int h = 2 * q + e;
      int t = tau * 32 + (h < 4 ? 4 * g2 + h : 16 + 4 * g2 + (h - 4));
      dst[h] = (_Float16)Ww[(size_t)i * 256 + t];
    }
  }
}

// out[b,i] = sum_j M[i,j] * V[b,j] for 8 batches per block.
// M row loaded once per thread, reused 8x -> M L2 traffic /8 vs per-batch.
__global__ void matvec8_k(const float* __restrict__ M, const float* __restrict__ V,
                          float* __restrict__ out)
{
  __shared__ float vb[8][256];
  const int i = threadIdx.x;
  const int b0 = blockIdx.x * 8;
#pragma unroll
  for (int r = 0; r < 8; ++r)
    vb[r][i] = V[(size_t)(b0 + r) * 256 + i];
  __syncthreads();
  float acc[8];
#pragma unroll
  for (int r = 0; r < 8; ++r) acc[r] = 0.f;
#pragma unroll 4
  for (int j = 0; j < 256; j += 4) {
    f4v m = *(const f4v*)(M + (size_t)i * 256 + j);
#pragma unroll
    for (int r = 0; r < 8; ++r) {
      f4v v = *(const f4v*)(&vb[r][j]);
      acc[r] += m[0] * v[0] + m[1] * v[1] + m[2] * v[2] + m[3] * v[3];
    }
  }
#pragma unroll
  for (int r = 0; r < 8; ++r)
    out[(size_t)(b0 + r) * 256 + i] = acc[r];
}

// ================= fused (1024 thr, 16 waves, 1 batch/block) ================
// GEMM tau-loop: pipelined GEMM2 (one tau behind), frag-order WT, WWS tribuf.
// Recurrence: VS carries [h*2^-7 ; -c*2^-7], FOUR iteration-local MFMA chains
// (no loop-carried accumulators -- r16 showed those spill; r18 showed phase
// merging spills; this exact schedule is the proven no-spill configuration).
__global__ __launch_bounds__(1024, 1) void fused_k(
    const float* __restrict__ w, const _Float16* __restrict__ wvp,
    const _Float16* __restrict__ wwp2, const _Float16* __restrict__ wup,
    const float* __restrict__ beta, float* __restrict__ cout)
{
  extern __shared__ char smem[];

  const int tid = threadIdx.x;
  const int wv = tid >> 6, lane = tid & 63;
  const int g = (lane >> 4) & 3, l15 = lane & 15;
  const int st_t = tid >> 5;            // staging row 0..31
  const int st_c = (tid & 31) * 8;      // staging col base (floats)
  const int B   = blockIdx.x;
  const float* wb = w + (size_t)B * 65536;

  // frag-order staging decomposition (round-15-verified mapping)
  const int c_   = tid & 31;
  const int wt_woff = ((c_ >> 2) * 2 + (st_t >> 4)) * WT_FRAG_STRIDE
                    + ((c_ & 1) * 32 + (st_t & 15)) * 16 + ((c_ >> 1) & 1) * 8;
#define WT_WRITE(off) { char* fb_ = smem + (off) + wt_woff; \
    *(u64*)fb_ = cvt4(sw[0]); *(u64*)(fb_ + 256) = cvt4(sw[1]); }

  f4v sw[2];                            // staged w (next-next tile)
  uint4 sws;                            // staged wwp2 slice (next-next)

  // ---- GEMM1 B-frags: fixed per wave, loaded once, reused all taus ----
  h8v bfv[8];
#pragma unroll
  for (int kk = 0; kk < 8; ++kk)
    bfv[kk] = *(const h8v*)(wvp + ((size_t)((wv * 8 + kk) * 64 + lane)) * 8);

  // prologue: w tile0 -> WT0; wws slice0 -> WWS0; reg-stage tile1/slice1
  {
    const float* src0 = wb + (size_t)st_t * 256 + st_c;
    sw[0] = *(const f4v*)(src0);
    sw[1] = *(const f4v*)(src0 + 4);
    WT_WRITE(WT0_OFF);
    *(uint4*)(smem + WWS0_OFF + tid * 16) =
        *(const uint4*)((const char*)wwp2 + tid * 16);
    const float* src1 = wb + (size_t)(32 + st_t) * 256 + st_c;
    sw[0] = *(const f4v*)(src1);
    sw[1] = *(const f4v*)(src1 + 4);
    sws = *(const uint4*)((const char*)wwp2 + 16384 + tid * 16);
    BAR();
  }

  f4v acc2[16];
#pragma unroll
  for (int it = 0; it < 16; ++it) acc2[it] = f4v{0.f, 0.f, 0.f, 0.f};

#pragma unroll
  for (int tau = 0; tau < 8; ++tau) {
    // A) write wt[(tau+1)&1] (frag order) and wws[(tau+1)%3] from staged regs
    if (tau < 7) {
      WT_WRITE(((tau + 1) & 1) ? WT1_OFF : WT0_OFF);
      *(uint4*)(smem + WWS0_OFF + ((tau + 1) % 3) * 16384 + tid * 16) = sws;
    }
    // B) issue loads for tau+2 (w tile + wws slice)
    if (tau < 6) {
      const float* src = wb + (size_t)((tau + 2) * 32 + st_t) * 256 + st_c;
      sw[0] = *(const f4v*)(src);
      sw[1] = *(const f4v*)(src + 4);
      sws = *(const uint4*)((const char*)wwp2 + (size_t)(tau + 2) * 16384 + tid * 16);
    }
    __builtin_amdgcn_s_setprio(1);
    // E) GEMM2(tau-1): acc2[it] += Tt(prev tau) * Ww  (independent of C/D)
    if (tau > 0) {
      const _Float16* ttr = (const _Float16*)(smem + (((tau - 1) & 1) ? TT1_OFF : TT0_OFF));
      h8v a0p; LDH(ttr + (wv * 16 + l15) * TT_STRIDE, 0, a0p);
      const char* wws = smem + WWS0_OFF + ((tau - 1) % 3) * 16384;
#pragma unroll
      for (int it = 0; it < 16; ++it) {
        h8v bf = *(const h8v*)(wws + (it * 64 + lane) * 16);
        acc2[it] = mfma16(a0p, bf, acc2[it]);
      }
    }
    // C) GEMM1(tau): contiguous b128 A-frag reads from frag-order WT
    f4v acc1[2];
    acc1[0] = f4v{0.f, 0.f, 0.f, 0.f};
    acc1[1] = f4v{0.f, 0.f, 0.f, 0.f};
    {
      const char* wtc = smem + ((tau & 1) ? WT1_OFF : WT0_OFF);
#pragma unroll
      for (int kk = 0; kk < 8; ++kk) {
        h8v a0 = *(const h8v*)(wtc + (kk * 2) * WT_FRAG_STRIDE + lane * 16);
        h8v a1 = *(const h8v*)(wtc + (kk * 2 + 1) * WT_FRAG_STRIDE + lane * 16);
        acc1[0] = mfma16(a0, bfv[kk], acc1[0]);
        acc1[1] = mfma16(a1, bfv[kk], acc1[1]);
      }
    }
    __builtin_amdgcn_s_setprio(0);
    // D) write Tt(tau) into TT[tau&1] (consumed by GEMM2 next phase)
    {
      _Float16* ttw = (_Float16*)(smem + ((tau & 1) ? TT1_OFF : TT0_OFF));
#pragma unroll
      for (int tm = 0; tm < 2; ++tm) {
        f4v a = acc1[tm];
        h4v t4; t4[0] = (_Float16)a[0]; t4[1] = (_Float16)a[1];
        t4[2] = (_Float16)a[2]; t4[3] = (_Float16)a[3];
        *(h4v*)(ttw + (wv * 16 + l15) * TT_STRIDE + tm * 16 + g * 4) = t4;
      }
    }
    // F) one barrier per tau
    BAR();
  } // tau

  // epilogue: GEMM2(7)
  {
    const _Float16* ttr = (const _Float16*)(smem + TT1_OFF);
    h8v a0p; LDH(ttr + (wv * 16 + l15) * TT_STRIDE, 0, a0p);
    const char* wws = smem + WWS0_OFF + (7 % 3) * 16384;
#pragma unroll
    for (int it = 0; it < 16; ++it) {
      h8v bf = *(const h8v*)(wws + (it * 64 + lane) * 16);
      acc2[it] = mfma16(a0p, bf, acc2[it]);
    }
  }
  BAR();   // all TT/WWS reads done before GC overlays them

  // ---- write FULL G into LDS ----
  // lane holds acc2[it] = G[i = it*16 + l15][j = wv*16 + 4g + reg]
  {
    _Float16* const GC = (_Float16*)(smem + GC_OFF);
#pragma unroll
    for (int it = 0; it < 16; ++it) {
      const int i = it * 16 + l15;
      f4v a = acc2[it];
      h4v t4; t4[0] = (_Float16)a[0]; t4[1] = (_Float16)a[1];
      t4[2] = (_Float16)a[2]; t4[3] = (_Float16)a[3];
      *(h4v*)(GC + (size_t)i * GC_STRIDE + wv * 16 + g * 4) = t4;
    }
  }
  // zero VS buffer 0 (h=0, c=0)
  if (tid < 256) ((u64*)(smem + VS_OFF))[tid] = 0ull;
  BAR();   // G + VS0 visible

  // ---- load A-frags of [Wu | G] for this wave's 16-row i-tile ----
  h8v af[16];
  {
    const int arow = wv * 16 + l15;
    const _Float16* wurow = wup + (size_t)arow * WUP_STRIDE;
#pragma unroll
    for (int kk = 0; kk < 8; ++kk) { LDH(wurow, kk, af[kk]); }
    const _Float16* gcrow = (const _Float16*)(smem + GC_OFF) + (size_t)arow * GC_STRIDE;
#pragma unroll
    for (int kk = 0; kk < 8; ++kk) { LDH(gcrow, kk, af[8 + kk]); }
  }
  f4v beta4 = *(const f4v*)(beta + (size_t)B * 256 + wv * 16 + 4 * g);
  f4v cm4 = f4v{0.f, 0.f, 0.f, 0.f};

  // producer slot for this (wv,g): byte offset within VS h-part / c-part
  const int vslot = (wv >> 1) * 64 + g * 16 + (wv & 1) * 8;

  for (int t = 0; t < 20; ++t) {
    const char* vsr = smem + VS_OFF + (t & 1) * 2048;
    f4v c0 = f4v{0.f, 0.f, 0.f, 0.f}, c1 = f4v{0.f, 0.f, 0.f, 0.f};
    f4v c2 = f4v{0.f, 0.f, 0.f, 0.f}, c3 = f4v{0.f, 0.f, 0.f, 0.f};
    __builtin_amdgcn_s_setprio(1);
#pragma unroll
    for (int kk = 0; kk < 16; kk += 4) {
      h8v v0 = *(const h8v*)(vsr + kk * 64 + g * 16);
      h8v v1 = *(const h8v*)(vsr + (kk + 1) * 64 + g * 16);
      h8v v2 = *(const h8v*)(vsr + (kk + 2) * 64 + g * 16);
      h8v v3 = *(const h8v*)(vsr + (kk + 3) * 64 + g * 16);
      c0 = mfma16(af[kk], v0, c0);
      c1 = mfma16(af[kk + 1], v1, c1);
      c2 = mfma16(af[kk + 2], v2, c2);
      c3 = mfma16(af[kk + 3], v3, c3);
    }
    __builtin_amdgcn_s_setprio(0);
    f4v y4 = (c0 + c1) + (c2 + c3);   // every D-column equals y
#pragma unroll
    for (int r = 0; r < 4; ++r) {
      float y = beta4[r] + y4[r] * 128.f;
      float hv = fmaxf(y, 0.f);
      cm4[r] += hv;
      y4[r] = hv;                      // reuse as h storage
    }
    char* vsw = smem + VS_OFF + ((t + 1) & 1) * 2048;
    if (l15 == 0) {
      h4v hh, ch;
#pragma unroll
      for (int r = 0; r < 4; ++r) {
        hh[r] = (_Float16)(y4[r] * 0.0078125f);     //  h * 2^-7
        ch[r] = (_Float16)(-cm4[r] * 0.0078125f);   // -c * 2^-7
      }
      *(u64*)(vsw + vslot)       = __builtin_bit_cast(u64, hh);
      *(u64*)(vsw + 512 + vslot) = __builtin_bit_cast(u64, ch);
    }
    BAR();
  }
  if (l15 == 0)
    *(f4v*)(cout + (size_t)B * 256 + wv * 16 + 4 * g) = cm4;
}

extern "C" void kernel_launch(void* const* d_in, const int* in_sizes, int n_in,
                              void* d_out, int out_size, void* d_ws, size_t ws_size,
                              hipStream_t stream)
{
  const float* w  = (const float*)d_in[0];
  const float* b  = (const float*)d_in[1];
  const float* Ww = (const float*)d_in[2];
  const float* Wu = (const float*)d_in[3];
  const float* Wv = (const float*)d_in[4];

  char* ws = (char*)d_ws;
  float*    beta = (float*)(ws);
  float*    cbuf = (float*)(ws + (size_t)2 * 1024 * 1024);
  _Float16* wvp  = (_Float16*)(ws + (size_t)4 * 1024 * 1024);
  _Float16* wwp2 = (_Float16*)(ws + (size_t)4 * 1024 * 1024 + 131072);
  _Float16* wup  = (_Float16*)(ws + (size_t)4 * 1024 * 1024 + 262144);

  (void)in_sizes; (void)n_in; (void)out_size; (void)ws_size;

  hipFuncSetAttribute((const void*)fused_k,
                      hipFuncAttributeMaxDynamicSharedMemorySize, LDS_FUSED);

  prep_k<<<256, 256, 0, stream>>>(Wu, wup);
  prep2_k<<<256, 256, 0, stream>>>(Wv, Ww, wvp, wwp2);
  matvec8_k<<<256, 256, 0, stream>>>(Ww, b, beta);                  // beta = Ww @ b
  fused_k<<<2048, 1024, LDS_FUSED, stream>>>(w, wvp, wwp2, wup, beta, cbuf);
  matvec8_k<<<256, 256, 0, stream>>>(Wv, cbuf, (float*)d_out);      // x = Wv @ c
}